// Round 8
// baseline (1561.731 us; speedup 1.0000x reference)
//
#include <hip/hip_runtime.h>
#include <hip/hip_cooperative_groups.h>

namespace cg = cooperative_groups;

#define NN 100000
#define CC 256
#define EE 3200000

#define SB 1024    // setup blocks (4/CU x 4 waves = 16 waves/CU, co-resident)
#define ST 256     // setup threads
#define CHUNK 98   // ceil(NN / SB)

typedef __attribute__((ext_vector_type(8))) short bf16x8;
typedef __attribute__((ext_vector_type(4))) float f32x4;
typedef __attribute__((ext_vector_type(4))) _Float16 f16x4;

__device__ __forceinline__ float4 f4add(float4 a, float4 b) {
  return make_float4(a.x + b.x, a.y + b.y, a.z + b.z, a.w + b.w);
}

__device__ __forceinline__ unsigned short f2bf(float f) {
  unsigned u = __float_as_uint(f);
  unsigned r = (u + 0x7fffu + ((u >> 16) & 1u)) >> 16;  // RTNE
  return (unsigned short)r;
}
__device__ __forceinline__ float bf2f(unsigned short h) {
  return __uint_as_float(((unsigned)h) << 16);
}

// ---- fused setup: zero+wsplit -> deg -> dis+chunk sums -> scan -> offs -> scatter
__global__ __launch_bounds__(ST) void k_setup(
    const int* __restrict__ src, const int* __restrict__ dst,
    const float* __restrict__ W1, const float* __restrict__ W2,
    int* __restrict__ cnt, float* __restrict__ dis,
    int* __restrict__ offs, int* __restrict__ bsum,
    int* __restrict__ bbase,
    unsigned short* __restrict__ W1h, unsigned short* __restrict__ W1l,
    unsigned short* __restrict__ W2h, unsigned short* __restrict__ W2l,
    int* __restrict__ csr) {
  cg::grid_group grid = cg::this_grid();
  const int tid = threadIdx.x;
  const int b = blockIdx.x;
  const int gtid = b * ST + tid;
  const int nthr = SB * ST;               // 262144
  const int lane = tid & 63, wv = tid >> 6;
  __shared__ int sh_w[4];

  // Phase A: zero cnt; split+transpose W1/W2 (65536 elements each)
  for (int i = gtid; i < NN; i += nthr) cnt[i] = 0;
  if (gtid < CC * CC) {
    int k = gtid >> 8, n = gtid & 255;
    float w1 = W1[k * CC + n];
    unsigned short h1 = f2bf(w1);
    W1h[n * CC + k] = h1;
    W1l[n * CC + k] = f2bf(w1 - bf2f(h1));
    float w2 = W2[k * CC + n];
    unsigned short h2 = f2bf(w2);
    W2h[n * CC + k] = h2;
    W2l[n * CC + k] = f2bf(w2 - bf2f(h2));
  }
  grid.sync();

  // Phase B: degree histogram (262k threads, ~12 edges each)
  for (int i = gtid; i < EE; i += nthr) {
    unsigned d = (unsigned)dst[i];
    if (d < NN) atomicAdd(&cnt[d], 1);
  }
  grid.sync();

  // Phase C1: per-chunk sums + dis
  const int c0 = b * CHUNK;
  const int c1e = (c0 + CHUNK < NN) ? c0 + CHUNK : NN;
  int lsum = 0;
  for (int i = c0 + tid; i < c1e; i += ST) {
    int c = cnt[i];
    lsum += c;
    dis[i] = 1.0f / sqrtf((float)(c + 1));
  }
  {
    int x = lsum;
#pragma unroll
    for (int d = 32; d > 0; d >>= 1) x += __shfl_down(x, d, 64);
    if (lane == 0) sh_w[wv] = x;
    __syncthreads();
    if (tid == 0) bsum[b] = sh_w[0] + sh_w[1] + sh_w[2] + sh_w[3];
  }
  grid.sync();

  // Phase C2: block 0 scans bsum[1024] -> bbase (exclusive), bbase[SB]=total
  if (b == 0) {
    __syncthreads();
    // each thread handles 4 consecutive entries
    int v0 = bsum[4 * tid + 0], v1 = bsum[4 * tid + 1];
    int v2 = bsum[4 * tid + 2], v3 = bsum[4 * tid + 3];
    int T = v0 + v1 + v2 + v3;
    int x = T;
#pragma unroll
    for (int d = 1; d < 64; d <<= 1) {
      int y = __shfl_up(x, d, 64);
      if (lane >= d) x += y;
    }
    if (lane == 63) sh_w[wv] = x;
    __syncthreads();
    int pre = 0;
#pragma unroll
    for (int w = 0; w < 4; ++w)
      if (w < wv) pre += sh_w[w];
    int base = pre + x - T;  // exclusive base for this thread's 4 entries
    bbase[4 * tid + 0] = base;
    bbase[4 * tid + 1] = base + v0;
    bbase[4 * tid + 2] = base + v0 + v1;
    bbase[4 * tid + 3] = base + v0 + v1 + v2;
    if (tid == 255) bbase[SB] = base + T;  // grand total
  }
  grid.sync();

  // Phase C3: per-chunk exclusive scan -> offs; zero cnt (becomes fill)
  {
    __syncthreads();
    int i0 = c0 + 2 * tid, i1 = i0 + 1;
    int v0 = (i0 < c1e) ? cnt[i0] : 0;
    int v1 = (i1 < c1e) ? cnt[i1] : 0;
    int p = v0 + v1, x = p;
#pragma unroll
    for (int d = 1; d < 64; d <<= 1) {
      int y = __shfl_up(x, d, 64);
      if (lane >= d) x += y;
    }
    if (lane == 63) sh_w[wv] = x;
    __syncthreads();
    int pre = 0;
#pragma unroll
    for (int w = 0; w < 4; ++w)
      if (w < wv) pre += sh_w[w];
    int base = bbase[b] + pre + x - p;
    if (i0 < c1e) { offs[i0] = base; cnt[i0] = 0; }
    if (i1 < c1e) { offs[i1] = base + v0; cnt[i1] = 0; }
    if (gtid == 0) offs[NN] = bbase[SB];
  }
  grid.sync();

  // Phase D: scatter src into CSR slots
  for (int i = gtid; i < EE; i += nthr) {
    unsigned d = (unsigned)dst[i];
    unsigned s = (unsigned)src[i];
    if (d < NN && s < NN) {
      int p = offs[d] + atomicAdd(&cnt[d], 1);
      csr[p] = (int)s;
    }
  }
}

// ---- split-bf16 MFMA GEMM, full-N block: Out[m][0..256) (fp16) ----
// 512 threads, 8 waves (2 m x 4 n), M-tile 128, N = 256 (all), K-tile 32.
// A*W ~= Ah*Wh + Al*Wh + Ah*Wl  (lo*lo ~2^-18 rel, dropped)
#define LDA 40  // ushort row stride: 80 B, 16B-aligned, breaks pow2 bank stride

__global__ __launch_bounds__(512) void k_gemm_mfma(
    const float* __restrict__ A, const unsigned short* __restrict__ WTh,
    const unsigned short* __restrict__ WTl, const float* __restrict__ dis,
    _Float16* __restrict__ Out, int M) {
  __shared__ unsigned short Ah[128 * LDA], Al[128 * LDA];   // 10 KB each
  __shared__ unsigned short Bh[256 * LDA], Bl[256 * LDA];   // 20 KB each
  const int tid = threadIdx.x;
  const int wave = tid >> 6, lane = tid & 63;
  const int quad = lane >> 4, l16 = lane & 15;
  const int wm = wave >> 2, wn = wave & 3;  // 2x4 wave grid, 64x64 each
  const int row0 = blockIdx.x * 128;

  f32x4 acc[4][4];
#pragma unroll
  for (int i = 0; i < 4; ++i)
#pragma unroll
    for (int j = 0; j < 4; ++j) acc[i][j] = (f32x4){0.f, 0.f, 0.f, 0.f};

  for (int k0 = 0; k0 < CC; k0 += 32) {
#pragma unroll
    for (int q = 0; q < 2; ++q) {
      int idx = tid + 512 * q;
      int r = idx >> 3;
      int c4 = (idx & 7) << 2;
      int gr = row0 + r;
      float4 v = make_float4(0.f, 0.f, 0.f, 0.f);
      if (gr < M) v = *(const float4*)&A[(size_t)gr * CC + k0 + c4];
      ushort4 hv, lv;
      hv.x = f2bf(v.x); lv.x = f2bf(v.x - bf2f(hv.x));
      hv.y = f2bf(v.y); lv.y = f2bf(v.y - bf2f(hv.y));
      hv.z = f2bf(v.z); lv.z = f2bf(v.z - bf2f(hv.z));
      hv.w = f2bf(v.w); lv.w = f2bf(v.w - bf2f(hv.w));
      *(ushort4*)&Ah[r * LDA + c4] = hv;
      *(ushort4*)&Al[r * LDA + c4] = lv;
    }
#pragma unroll
    for (int q = 0; q < 4; ++q) {
      int idx = tid + 512 * q;
      int r = idx >> 3;
      int c4 = (idx & 7) << 2;
      const size_t g = (size_t)r * CC + k0 + c4;
      *(ushort4*)&Bh[r * LDA + c4] = *(const ushort4*)&WTh[g];
      *(ushort4*)&Bl[r * LDA + c4] = *(const ushort4*)&WTl[g];
    }
    __syncthreads();

    bf16x8 bh[4], bl[4];
#pragma unroll
    for (int j = 0; j < 4; ++j) {
      int br = (wn * 64 + j * 16 + l16) * LDA + quad * 8;
      bh[j] = *(const bf16x8*)&Bh[br];
      bl[j] = *(const bf16x8*)&Bl[br];
    }
#pragma unroll
    for (int i = 0; i < 4; ++i) {
      int ar = (wm * 64 + i * 16 + l16) * LDA + quad * 8;
      bf16x8 ah = *(const bf16x8*)&Ah[ar];
      bf16x8 al = *(const bf16x8*)&Al[ar];
#pragma unroll
      for (int j = 0; j < 4; ++j) {
        acc[i][j] = __builtin_amdgcn_mfma_f32_16x16x32_bf16(ah, bh[j], acc[i][j], 0, 0, 0);
        acc[i][j] = __builtin_amdgcn_mfma_f32_16x16x32_bf16(al, bh[j], acc[i][j], 0, 0, 0);
        acc[i][j] = __builtin_amdgcn_mfma_f32_16x16x32_bf16(ah, bl[j], acc[i][j], 0, 0, 0);
      }
    }
    __syncthreads();
  }

  // epilogue: D layout col=lane&15, row=quad*4+reg (m89-verified); fp16 store
#pragma unroll
  for (int i = 0; i < 4; ++i) {
#pragma unroll
    for (int r4 = 0; r4 < 4; ++r4) {
      int r = row0 + wm * 64 + i * 16 + quad * 4 + r4;
      if (r < M) {
        float sc = dis[r];
#pragma unroll
        for (int j = 0; j < 4; ++j) {
          Out[(size_t)r * CC + wn * 64 + j * 16 + l16] =
              (_Float16)(acc[i][j][r4] * sc);
        }
      }
    }
  }
}

// ---- CSR aggregation (fp16 gather, 8-wide): h1[i]=relu(dis*(sum+self)+b) ----
__global__ __launch_bounds__(256) void k_aggregate(
    const _Float16* __restrict__ hs, const int* __restrict__ offs,
    const int* __restrict__ csr, const float* __restrict__ dis,
    const float* __restrict__ bias, float* __restrict__ out, int n) {
  int node = blockIdx.x * 4 + (threadIdx.x >> 6);
  if (node >= n) return;
  int lane = threadIdx.x & 63;
  int c4 = lane << 2;
  int beg = offs[node], end = offs[node + 1];
  f16x4 sv = *(const f16x4*)&hs[(size_t)node * CC + c4];  // self-loop term
  float4 a0 = make_float4((float)sv.x, (float)sv.y, (float)sv.z, (float)sv.w);
  float4 a1 = make_float4(0.f, 0.f, 0.f, 0.f);
  float4 a2 = make_float4(0.f, 0.f, 0.f, 0.f);
  float4 a3 = make_float4(0.f, 0.f, 0.f, 0.f);
  int e = beg;
  for (; e + 8 <= end; e += 8) {
    int s0 = csr[e],     s1 = csr[e + 1], s2 = csr[e + 2], s3 = csr[e + 3];
    int s4 = csr[e + 4], s5 = csr[e + 5], s6 = csr[e + 6], s7 = csr[e + 7];
    f16x4 v0 = *(const f16x4*)&hs[(size_t)s0 * CC + c4];
    f16x4 v1 = *(const f16x4*)&hs[(size_t)s1 * CC + c4];
    f16x4 v2 = *(const f16x4*)&hs[(size_t)s2 * CC + c4];
    f16x4 v3 = *(const f16x4*)&hs[(size_t)s3 * CC + c4];
    f16x4 v4 = *(const f16x4*)&hs[(size_t)s4 * CC + c4];
    f16x4 v5 = *(const f16x4*)&hs[(size_t)s5 * CC + c4];
    f16x4 v6 = *(const f16x4*)&hs[(size_t)s6 * CC + c4];
    f16x4 v7 = *(const f16x4*)&hs[(size_t)s7 * CC + c4];
    a0.x += (float)v0.x + (float)v4.x; a0.y += (float)v0.y + (float)v4.y;
    a0.z += (float)v0.z + (float)v4.z; a0.w += (float)v0.w + (float)v4.w;
    a1.x += (float)v1.x + (float)v5.x; a1.y += (float)v1.y + (float)v5.y;
    a1.z += (float)v1.z + (float)v5.z; a1.w += (float)v1.w + (float)v5.w;
    a2.x += (float)v2.x + (float)v6.x; a2.y += (float)v2.y + (float)v6.y;
    a2.z += (float)v2.z + (float)v6.z; a2.w += (float)v2.w + (float)v6.w;
    a3.x += (float)v3.x + (float)v7.x; a3.y += (float)v3.y + (float)v7.y;
    a3.z += (float)v3.z + (float)v7.z; a3.w += (float)v3.w + (float)v7.w;
  }
  for (; e + 2 <= end; e += 2) {
    int s0 = csr[e], s1 = csr[e + 1];
    f16x4 v0 = *(const f16x4*)&hs[(size_t)s0 * CC + c4];
    f16x4 v1 = *(const f16x4*)&hs[(size_t)s1 * CC + c4];
    a0.x += (float)v0.x; a0.y += (float)v0.y; a0.z += (float)v0.z; a0.w += (float)v0.w;
    a1.x += (float)v1.x; a1.y += (float)v1.y; a1.z += (float)v1.z; a1.w += (float)v1.w;
  }
  if (e < end) {
    int s0 = csr[e];
    f16x4 v0 = *(const f16x4*)&hs[(size_t)s0 * CC + c4];
    a0.x += (float)v0.x; a0.y += (float)v0.y; a0.z += (float)v0.z; a0.w += (float)v0.w;
  }
  float4 acc = f4add(f4add(a0, a1), f4add(a2, a3));
  float sc = dis[node];
  float4 bv = *(const float4*)&bias[c4];
  float4 r;
  r.x = fmaxf(acc.x * sc + bv.x, 0.f);
  r.y = fmaxf(acc.y * sc + bv.y, 0.f);
  r.z = fmaxf(acc.z * sc + bv.z, 0.f);
  r.w = fmaxf(acc.w * sc + bv.w, 0.f);
  *(float4*)&out[(size_t)node * CC + c4] = r;
}

// ---- fused layer-2 aggregate + readout: out[i] = relu(...) . Wl + bl ----
__global__ __launch_bounds__(256) void k_aggregate_final(
    const _Float16* __restrict__ hs, const int* __restrict__ offs,
    const int* __restrict__ csr, const float* __restrict__ dis,
    const float* __restrict__ bias, const float* __restrict__ Wl,
    const float* __restrict__ bl, float* __restrict__ out, int n) {
  int node = blockIdx.x * 4 + (threadIdx.x >> 6);
  if (node >= n) return;
  int lane = threadIdx.x & 63;
  int c4 = lane << 2;
  int beg = offs[node], end = offs[node + 1];
  f16x4 sv = *(const f16x4*)&hs[(size_t)node * CC + c4];
  float4 a0 = make_float4((float)sv.x, (float)sv.y, (float)sv.z, (float)sv.w);
  float4 a1 = make_float4(0.f, 0.f, 0.f, 0.f);
  float4 a2 = make_float4(0.f, 0.f, 0.f, 0.f);
  float4 a3 = make_float4(0.f, 0.f, 0.f, 0.f);
  int e = beg;
  for (; e + 8 <= end; e += 8) {
    int s0 = csr[e],     s1 = csr[e + 1], s2 = csr[e + 2], s3 = csr[e + 3];
    int s4 = csr[e + 4], s5 = csr[e + 5], s6 = csr[e + 6], s7 = csr[e + 7];
    f16x4 v0 = *(const f16x4*)&hs[(size_t)s0 * CC + c4];
    f16x4 v1 = *(const f16x4*)&hs[(size_t)s1 * CC + c4];
    f16x4 v2 = *(const f16x4*)&hs[(size_t)s2 * CC + c4];
    f16x4 v3 = *(const f16x4*)&hs[(size_t)s3 * CC + c4];
    f16x4 v4 = *(const f16x4*)&hs[(size_t)s4 * CC + c4];
    f16x4 v5 = *(const f16x4*)&hs[(size_t)s5 * CC + c4];
    f16x4 v6 = *(const f16x4*)&hs[(size_t)s6 * CC + c4];
    f16x4 v7 = *(const f16x4*)&hs[(size_t)s7 * CC + c4];
    a0.x += (float)v0.x + (float)v4.x; a0.y += (float)v0.y + (float)v4.y;
    a0.z += (float)v0.z + (float)v4.z; a0.w += (float)v0.w + (float)v4.w;
    a1.x += (float)v1.x + (float)v5.x; a1.y += (float)v1.y + (float)v5.y;
    a1.z += (float)v1.z + (float)v5.z; a1.w += (float)v1.w + (float)v5.w;
    a2.x += (float)v2.x + (float)v6.x; a2.y += (float)v2.y + (float)v6.y;
    a2.z += (float)v2.z + (float)v6.z; a2.w += (float)v2.w + (float)v6.w;
    a3.x += (float)v3.x + (float)v7.x; a3.y += (float)v3.y + (float)v7.y;
    a3.z += (float)v3.z + (float)v7.z; a3.w += (float)v3.w + (float)v7.w;
  }
  for (; e + 2 <= end; e += 2) {
    int s0 = csr[e], s1 = csr[e + 1];
    f16x4 v0 = *(const f16x4*)&hs[(size_t)s0 * CC + c4];
    f16x4 v1 = *(const f16x4*)&hs[(size_t)s1 * CC + c4];
    a0.x += (float)v0.x; a0.y += (float)v0.y; a0.z += (float)v0.z; a0.w += (float)v0.w;
    a1.x += (float)v1.x; a1.y += (float)v1.y; a1.z += (float)v1.z; a1.w += (float)v1.w;
  }
  if (e < end) {
    int s0 = csr[e];
    f16x4 v0 = *(const f16x4*)&hs[(size_t)s0 * CC + c4];
    a0.x += (float)v0.x; a0.y += (float)v0.y; a0.z += (float)v0.z; a0.w += (float)v0.w;
  }
  float4 acc = f4add(f4add(a0, a1), f4add(a2, a3));
  float sc = dis[node];
  float4 bv = *(const float4*)&bias[c4];
  float4 w = *(const float4*)&Wl[c4];
  float s = fmaxf(acc.x * sc + bv.x, 0.f) * w.x +
            fmaxf(acc.y * sc + bv.y, 0.f) * w.y +
            fmaxf(acc.z * sc + bv.z, 0.f) * w.z +
            fmaxf(acc.w * sc + bv.w, 0.f) * w.w;
#pragma unroll
  for (int d = 32; d > 0; d >>= 1) s += __shfl_down(s, d, 64);
  if (lane == 0) out[node] = s + bl[0];
}

extern "C" void kernel_launch(void* const* d_in, const int* in_sizes, int n_in,
                              void* d_out, int out_size, void* d_ws, size_t ws_size,
                              hipStream_t stream) {
  const float* x = (const float*)d_in[0];
  const int* ei = (const int*)d_in[1];  // int64 in reference -> int32 on device
  const float* W1 = (const float*)d_in[2];
  const float* b1 = (const float*)d_in[3];
  const float* W2 = (const float*)d_in[4];
  const float* b2 = (const float*)d_in[5];
  const float* Wl = (const float*)d_in[6];
  const float* bl = (const float*)d_in[7];
  float* out = (float*)d_out;

  const int* srcp = ei;
  const int* dstp = ei + EE;

  char* ws = (char*)d_ws;
  size_t off = 0;
  auto alloc = [&](size_t bytes) {
    char* p = ws + off;
    off = (off + bytes + 255) & ~(size_t)255;
    return p;
  };
  float* dis = (float*)alloc((size_t)NN * 4);
  int* cnt = (int*)alloc((size_t)NN * 4);   // degrees, then fill counters
  int* offs = (int*)alloc((size_t)(NN + 1) * 4);
  int* bsum = (int*)alloc((SB + 8) * 4);
  int* bbase = (int*)alloc((SB + 8) * 4);
  int* csr = (int*)alloc((size_t)EE * 4);
  unsigned short* W1h = (unsigned short*)alloc((size_t)CC * CC * 2);
  unsigned short* W1l = (unsigned short*)alloc((size_t)CC * CC * 2);
  unsigned short* W2h = (unsigned short*)alloc((size_t)CC * CC * 2);
  unsigned short* W2l = (unsigned short*)alloc((size_t)CC * CC * 2);
  _Float16* hsbuf = (_Float16*)alloc((size_t)NN * CC * 2);  // GEMM out (fp16)
  float* h1 = (float*)alloc((size_t)NN * CC * 4);           // layer-1 activations

  // ---- one cooperative setup kernel, 1024 blocks (262k threads) ----
  {
    void* args[] = {(void*)&srcp, (void*)&dstp, (void*)&W1, (void*)&W2,
                    (void*)&cnt, (void*)&dis, (void*)&offs, (void*)&bsum,
                    (void*)&bbase, (void*)&W1h, (void*)&W1l, (void*)&W2h,
                    (void*)&W2l, (void*)&csr};
    hipLaunchCooperativeKernel((const void*)k_setup, dim3(SB), dim3(ST),
                               args, 0, stream);
  }

  const int gblocks = (NN + 127) / 128;
  // layer 1: hs = (x @ W1) * dis[row] (fp16); h1 = relu(dis*(agg+self) + b1)
  k_gemm_mfma<<<gblocks, 512, 0, stream>>>(x, W1h, W1l, dis, hsbuf, NN);
  k_aggregate<<<(NN + 3) / 4, 256, 0, stream>>>(hsbuf, offs, csr, dis, b1, h1, NN);
  // layer 2 + fused readout
  k_gemm_mfma<<<gblocks, 512, 0, stream>>>(h1, W2h, W2l, dis, hsbuf, NN);
  k_aggregate_final<<<(NN + 3) / 4, 256, 0, stream>>>(hsbuf, offs, csr, dis, b2, Wl, bl, out, NN);
}

// Round 9
// 1047.654 us; speedup vs baseline: 1.4907x; 1.4907x over previous
//
#include <hip/hip_runtime.h>

#define NN 100000
#define CC 256
#define EE 3200000

typedef __attribute__((ext_vector_type(8))) short bf16x8;
typedef __attribute__((ext_vector_type(4))) float f32x4;
typedef __attribute__((ext_vector_type(4))) _Float16 f16x4;

__device__ __forceinline__ float4 f4add(float4 a, float4 b) {
  return make_float4(a.x + b.x, a.y + b.y, a.z + b.z, a.w + b.w);
}

__device__ __forceinline__ unsigned short f2bf(float f) {
  unsigned u = __float_as_uint(f);
  unsigned r = (u + 0x7fffu + ((u >> 16) & 1u)) >> 16;  // RTNE
  return (unsigned short)r;
}
__device__ __forceinline__ float bf2f(unsigned short h) {
  return __uint_as_float(((unsigned)h) << 16);
}

// ---- degree histogram ----
__global__ void k_deg(const int* __restrict__ dst, int* __restrict__ cnt, int n) {
  int i = blockIdx.x * blockDim.x + threadIdx.x;
  int stride = gridDim.x * blockDim.x;
  for (; i < n; i += stride) {
    unsigned d = (unsigned)dst[i];
    if (d < NN) atomicAdd(&cnt[d], 1);
  }
}

// ---- scan phase 1: per-1024-chunk exclusive scan + chunk sums + dis ----
__global__ void k_scan_local(const int* __restrict__ cnt, int* __restrict__ offs,
                             int* __restrict__ bsum, float* __restrict__ dis, int n) {
  __shared__ int wsum[16];
  int t = threadIdx.x;
  int idx = blockIdx.x * 1024 + t;
  int lane = t & 63, wv = t >> 6;
  int v = (idx < n) ? cnt[idx] : 0;
  if (idx < n) dis[idx] = 1.0f / sqrtf((float)(v + 1));
  int x = v;
#pragma unroll
  for (int d = 1; d < 64; d <<= 1) {
    int y = __shfl_up(x, d, 64);
    if (lane >= d) x += y;
  }
  if (lane == 63) wsum[wv] = x;
  __syncthreads();
  int wpre = 0, total = 0;
#pragma unroll
  for (int w = 0; w < 16; ++w) {
    int s = wsum[w];
    if (w < wv) wpre += s;
    total += s;
  }
  if (idx < n) offs[idx] = wpre + x - v;
  if (t == 0) bsum[blockIdx.x] = total;
}

// ---- scan phase 2: scan the 98 chunk sums ----
__global__ void k_scan_bsum(const int* __restrict__ bsum, int* __restrict__ bbase, int nb) {
  __shared__ int wsum[2];
  int t = threadIdx.x;  // 128 threads, nb <= 128
  int lane = t & 63, wv = t >> 6;
  int v = (t < nb) ? bsum[t] : 0;
  int x = v;
#pragma unroll
  for (int d = 1; d < 64; d <<= 1) {
    int y = __shfl_up(x, d, 64);
    if (lane >= d) x += y;
  }
  if (lane == 63) wsum[wv] = x;
  __syncthreads();
  int pre = (wv == 1) ? wsum[0] : 0;
  if (t < nb) bbase[t] = pre + x - v;
  if (t == nb - 1) bbase[nb] = pre + x;  // grand total
}

// ---- scan phase 3: add chunk bases; zero cnt (becomes fill counters) ----
__global__ void k_scan_add(int* __restrict__ offs, const int* __restrict__ bbase,
                           int* __restrict__ cnt, int n, int nb) {
  int i = blockIdx.x * 256 + threadIdx.x;
  if (i < n) {
    offs[i] += bbase[i >> 10];
    cnt[i] = 0;
  }
  if (i == 0) offs[n] = bbase[nb];
}

// ---- scatter edge src indices into CSR slots ----
__global__ void k_scatter(const int* __restrict__ src, const int* __restrict__ dst,
                          const int* __restrict__ offs, int* __restrict__ fill,
                          int* __restrict__ csr, int n) {
  int i = blockIdx.x * blockDim.x + threadIdx.x;
  int stride = gridDim.x * blockDim.x;
  for (; i < n; i += stride) {
    unsigned d = (unsigned)dst[i];
    unsigned s = (unsigned)src[i];
    if (d < NN && s < NN) {
      int p = offs[d] + atomicAdd(&fill[d], 1);
      csr[p] = (int)s;
    }
  }
}

// ---- split BOTH weights (fp32) into transposed bf16 hi/lo in one dispatch ----
__global__ void k_wsplit2(const float* __restrict__ W1, const float* __restrict__ W2,
                          unsigned short* __restrict__ W1h, unsigned short* __restrict__ W1l,
                          unsigned short* __restrict__ W2h, unsigned short* __restrict__ W2l) {
  int b = blockIdx.x, t = threadIdx.x;
  int idx = (b & 255) * 256 + t;
  int k = idx >> 8, n = idx & 255;
  if (b < 256) {
    float w = W1[k * CC + n];
    unsigned short h = f2bf(w);
    W1h[n * CC + k] = h;
    W1l[n * CC + k] = f2bf(w - bf2f(h));
  } else {
    float w = W2[k * CC + n];
    unsigned short h = f2bf(w);
    W2h[n * CC + k] = h;
    W2l[n * CC + k] = f2bf(w - bf2f(h));
  }
}

// ---- split-bf16 MFMA GEMM, full-N block: Out[m][0..256) (fp16) ----
// 512 threads, 8 waves (2 m x 4 n), M-tile 128, N = 256 (all), K-tile 32.
// A*W ~= Ah*Wh + Al*Wh + Ah*Wl  (lo*lo ~2^-18 rel, dropped)
#define LDA 40  // ushort row stride: 80 B, 16B-aligned, breaks pow2 bank stride

__global__ __launch_bounds__(512) void k_gemm_mfma(
    const float* __restrict__ A, const unsigned short* __restrict__ WTh,
    const unsigned short* __restrict__ WTl, const float* __restrict__ dis,
    _Float16* __restrict__ Out, int M) {
  __shared__ unsigned short Ah[128 * LDA], Al[128 * LDA];   // 10 KB each
  __shared__ unsigned short Bh[256 * LDA], Bl[256 * LDA];   // 20 KB each
  const int tid = threadIdx.x;
  const int wave = tid >> 6, lane = tid & 63;
  const int quad = lane >> 4, l16 = lane & 15;
  const int wm = wave >> 2, wn = wave & 3;  // 2x4 wave grid, 64x64 each
  const int row0 = blockIdx.x * 128;

  f32x4 acc[4][4];
#pragma unroll
  for (int i = 0; i < 4; ++i)
#pragma unroll
    for (int j = 0; j < 4; ++j) acc[i][j] = (f32x4){0.f, 0.f, 0.f, 0.f};

  for (int k0 = 0; k0 < CC; k0 += 32) {
#pragma unroll
    for (int q = 0; q < 2; ++q) {
      int idx = tid + 512 * q;
      int r = idx >> 3;
      int c4 = (idx & 7) << 2;
      int gr = row0 + r;
      float4 v = make_float4(0.f, 0.f, 0.f, 0.f);
      if (gr < M) v = *(const float4*)&A[(size_t)gr * CC + k0 + c4];
      ushort4 hv, lv;
      hv.x = f2bf(v.x); lv.x = f2bf(v.x - bf2f(hv.x));
      hv.y = f2bf(v.y); lv.y = f2bf(v.y - bf2f(hv.y));
      hv.z = f2bf(v.z); lv.z = f2bf(v.z - bf2f(hv.z));
      hv.w = f2bf(v.w); lv.w = f2bf(v.w - bf2f(hv.w));
      *(ushort4*)&Ah[r * LDA + c4] = hv;
      *(ushort4*)&Al[r * LDA + c4] = lv;
    }
#pragma unroll
    for (int q = 0; q < 4; ++q) {
      int idx = tid + 512 * q;
      int r = idx >> 3;
      int c4 = (idx & 7) << 2;
      const size_t g = (size_t)r * CC + k0 + c4;
      *(ushort4*)&Bh[r * LDA + c4] = *(const ushort4*)&WTh[g];
      *(ushort4*)&Bl[r * LDA + c4] = *(const ushort4*)&WTl[g];
    }
    __syncthreads();

    bf16x8 bh[4], bl[4];
#pragma unroll
    for (int j = 0; j < 4; ++j) {
      int br = (wn * 64 + j * 16 + l16) * LDA + quad * 8;
      bh[j] = *(const bf16x8*)&Bh[br];
      bl[j] = *(const bf16x8*)&Bl[br];
    }
#pragma unroll
    for (int i = 0; i < 4; ++i) {
      int ar = (wm * 64 + i * 16 + l16) * LDA + quad * 8;
      bf16x8 ah = *(const bf16x8*)&Ah[ar];
      bf16x8 al = *(const bf16x8*)&Al[ar];
#pragma unroll
      for (int j = 0; j < 4; ++j) {
        acc[i][j] = __builtin_amdgcn_mfma_f32_16x16x32_bf16(ah, bh[j], acc[i][j], 0, 0, 0);
        acc[i][j] = __builtin_amdgcn_mfma_f32_16x16x32_bf16(al, bh[j], acc[i][j], 0, 0, 0);
        acc[i][j] = __builtin_amdgcn_mfma_f32_16x16x32_bf16(ah, bl[j], acc[i][j], 0, 0, 0);
      }
    }
    __syncthreads();
  }

  // epilogue: D layout col=lane&15, row=quad*4+reg (m89-verified); fp16 store
#pragma unroll
  for (int i = 0; i < 4; ++i) {
#pragma unroll
    for (int r4 = 0; r4 < 4; ++r4) {
      int r = row0 + wm * 64 + i * 16 + quad * 4 + r4;
      if (r < M) {
        float sc = dis[r];
#pragma unroll
        for (int j = 0; j < 4; ++j) {
          Out[(size_t)r * CC + wn * 64 + j * 16 + l16] =
              (_Float16)(acc[i][j][r4] * sc);
        }
      }
    }
  }
}

// ---- CSR aggregation (fp16 gather, 8-wide): h1[i]=relu(dis*(sum+self)+b) ----
__global__ __launch_bounds__(256) void k_aggregate(
    const _Float16* __restrict__ hs, const int* __restrict__ offs,
    const int* __restrict__ csr, const float* __restrict__ dis,
    const float* __restrict__ bias, float* __restrict__ out, int n) {
  int node = blockIdx.x * 4 + (threadIdx.x >> 6);
  if (node >= n) return;
  int lane = threadIdx.x & 63;
  int c4 = lane << 2;
  int beg = offs[node], end = offs[node + 1];
  f16x4 sv = *(const f16x4*)&hs[(size_t)node * CC + c4];  // self-loop term
  float4 a0 = make_float4((float)sv.x, (float)sv.y, (float)sv.z, (float)sv.w);
  float4 a1 = make_float4(0.f, 0.f, 0.f, 0.f);
  float4 a2 = make_float4(0.f, 0.f, 0.f, 0.f);
  float4 a3 = make_float4(0.f, 0.f, 0.f, 0.f);
  int e = beg;
  for (; e + 8 <= end; e += 8) {
    int s0 = csr[e],     s1 = csr[e + 1], s2 = csr[e + 2], s3 = csr[e + 3];
    int s4 = csr[e + 4], s5 = csr[e + 5], s6 = csr[e + 6], s7 = csr[e + 7];
    f16x4 v0 = *(const f16x4*)&hs[(size_t)s0 * CC + c4];
    f16x4 v1 = *(const f16x4*)&hs[(size_t)s1 * CC + c4];
    f16x4 v2 = *(const f16x4*)&hs[(size_t)s2 * CC + c4];
    f16x4 v3 = *(const f16x4*)&hs[(size_t)s3 * CC + c4];
    f16x4 v4 = *(const f16x4*)&hs[(size_t)s4 * CC + c4];
    f16x4 v5 = *(const f16x4*)&hs[(size_t)s5 * CC + c4];
    f16x4 v6 = *(const f16x4*)&hs[(size_t)s6 * CC + c4];
    f16x4 v7 = *(const f16x4*)&hs[(size_t)s7 * CC + c4];
    a0.x += (float)v0.x + (float)v4.x; a0.y += (float)v0.y + (float)v4.y;
    a0.z += (float)v0.z + (float)v4.z; a0.w += (float)v0.w + (float)v4.w;
    a1.x += (float)v1.x + (float)v5.x; a1.y += (float)v1.y + (float)v5.y;
    a1.z += (float)v1.z + (float)v5.z; a1.w += (float)v1.w + (float)v5.w;
    a2.x += (float)v2.x + (float)v6.x; a2.y += (float)v2.y + (float)v6.y;
    a2.z += (float)v2.z + (float)v6.z; a2.w += (float)v2.w + (float)v6.w;
    a3.x += (float)v3.x + (float)v7.x; a3.y += (float)v3.y + (float)v7.y;
    a3.z += (float)v3.z + (float)v7.z; a3.w += (float)v3.w + (float)v7.w;
  }
  for (; e + 2 <= end; e += 2) {
    int s0 = csr[e], s1 = csr[e + 1];
    f16x4 v0 = *(const f16x4*)&hs[(size_t)s0 * CC + c4];
    f16x4 v1 = *(const f16x4*)&hs[(size_t)s1 * CC + c4];
    a0.x += (float)v0.x; a0.y += (float)v0.y; a0.z += (float)v0.z; a0.w += (float)v0.w;
    a1.x += (float)v1.x; a1.y += (float)v1.y; a1.z += (float)v1.z; a1.w += (float)v1.w;
  }
  if (e < end) {
    int s0 = csr[e];
    f16x4 v0 = *(const f16x4*)&hs[(size_t)s0 * CC + c4];
    a0.x += (float)v0.x; a0.y += (float)v0.y; a0.z += (float)v0.z; a0.w += (float)v0.w;
  }
  float4 acc = f4add(f4add(a0, a1), f4add(a2, a3));
  float sc = dis[node];
  float4 bv = *(const float4*)&bias[c4];
  float4 r;
  r.x = fmaxf(acc.x * sc + bv.x, 0.f);
  r.y = fmaxf(acc.y * sc + bv.y, 0.f);
  r.z = fmaxf(acc.z * sc + bv.z, 0.f);
  r.w = fmaxf(acc.w * sc + bv.w, 0.f);
  *(float4*)&out[(size_t)node * CC + c4] = r;
}

// ---- fused layer-2 aggregate + readout: out[i] = relu(...) . Wl + bl ----
__global__ __launch_bounds__(256) void k_aggregate_final(
    const _Float16* __restrict__ hs, const int* __restrict__ offs,
    const int* __restrict__ csr, const float* __restrict__ dis,
    const float* __restrict__ bias, const float* __restrict__ Wl,
    const float* __restrict__ bl, float* __restrict__ out, int n) {
  int node = blockIdx.x * 4 + (threadIdx.x >> 6);
  if (node >= n) return;
  int lane = threadIdx.x & 63;
  int c4 = lane << 2;
  int beg = offs[node], end = offs[node + 1];
  f16x4 sv = *(const f16x4*)&hs[(size_t)node * CC + c4];
  float4 a0 = make_float4((float)sv.x, (float)sv.y, (float)sv.z, (float)sv.w);
  float4 a1 = make_float4(0.f, 0.f, 0.f, 0.f);
  float4 a2 = make_float4(0.f, 0.f, 0.f, 0.f);
  float4 a3 = make_float4(0.f, 0.f, 0.f, 0.f);
  int e = beg;
  for (; e + 8 <= end; e += 8) {
    int s0 = csr[e],     s1 = csr[e + 1], s2 = csr[e + 2], s3 = csr[e + 3];
    int s4 = csr[e + 4], s5 = csr[e + 5], s6 = csr[e + 6], s7 = csr[e + 7];
    f16x4 v0 = *(const f16x4*)&hs[(size_t)s0 * CC + c4];
    f16x4 v1 = *(const f16x4*)&hs[(size_t)s1 * CC + c4];
    f16x4 v2 = *(const f16x4*)&hs[(size_t)s2 * CC + c4];
    f16x4 v3 = *(const f16x4*)&hs[(size_t)s3 * CC + c4];
    f16x4 v4 = *(const f16x4*)&hs[(size_t)s4 * CC + c4];
    f16x4 v5 = *(const f16x4*)&hs[(size_t)s5 * CC + c4];
    f16x4 v6 = *(const f16x4*)&hs[(size_t)s6 * CC + c4];
    f16x4 v7 = *(const f16x4*)&hs[(size_t)s7 * CC + c4];
    a0.x += (float)v0.x + (float)v4.x; a0.y += (float)v0.y + (float)v4.y;
    a0.z += (float)v0.z + (float)v4.z; a0.w += (float)v0.w + (float)v4.w;
    a1.x += (float)v1.x + (float)v5.x; a1.y += (float)v1.y + (float)v5.y;
    a1.z += (float)v1.z + (float)v5.z; a1.w += (float)v1.w + (float)v5.w;
    a2.x += (float)v2.x + (float)v6.x; a2.y += (float)v2.y + (float)v6.y;
    a2.z += (float)v2.z + (float)v6.z; a2.w += (float)v2.w + (float)v6.w;
    a3.x += (float)v3.x + (float)v7.x; a3.y += (float)v3.y + (float)v7.y;
    a3.z += (float)v3.z + (float)v7.z; a3.w += (float)v3.w + (float)v7.w;
  }
  for (; e + 2 <= end; e += 2) {
    int s0 = csr[e], s1 = csr[e + 1];
    f16x4 v0 = *(const f16x4*)&hs[(size_t)s0 * CC + c4];
    f16x4 v1 = *(const f16x4*)&hs[(size_t)s1 * CC + c4];
    a0.x += (float)v0.x; a0.y += (float)v0.y; a0.z += (float)v0.z; a0.w += (float)v0.w;
    a1.x += (float)v1.x; a1.y += (float)v1.y; a1.z += (float)v1.z; a1.w += (float)v1.w;
  }
  if (e < end) {
    int s0 = csr[e];
    f16x4 v0 = *(const f16x4*)&hs[(size_t)s0 * CC + c4];
    a0.x += (float)v0.x; a0.y += (float)v0.y; a0.z += (float)v0.z; a0.w += (float)v0.w;
  }
  float4 acc = f4add(f4add(a0, a1), f4add(a2, a3));
  float sc = dis[node];
  float4 bv = *(const float4*)&bias[c4];
  float4 w = *(const float4*)&Wl[c4];
  float s = fmaxf(acc.x * sc + bv.x, 0.f) * w.x +
            fmaxf(acc.y * sc + bv.y, 0.f) * w.y +
            fmaxf(acc.z * sc + bv.z, 0.f) * w.z +
            fmaxf(acc.w * sc + bv.w, 0.f) * w.w;
#pragma unroll
  for (int d = 32; d > 0; d >>= 1) s += __shfl_down(s, d, 64);
  if (lane == 0) out[node] = s + bl[0];
}

extern "C" void kernel_launch(void* const* d_in, const int* in_sizes, int n_in,
                              void* d_out, int out_size, void* d_ws, size_t ws_size,
                              hipStream_t stream) {
  const float* x = (const float*)d_in[0];
  const int* ei = (const int*)d_in[1];  // int64 in reference -> int32 on device
  const float* W1 = (const float*)d_in[2];
  const float* b1 = (const float*)d_in[3];
  const float* W2 = (const float*)d_in[4];
  const float* b2 = (const float*)d_in[5];
  const float* Wl = (const float*)d_in[6];
  const float* bl = (const float*)d_in[7];
  float* out = (float*)d_out;

  const int* src = ei;
  const int* dst = ei + EE;

  char* ws = (char*)d_ws;
  size_t off = 0;
  auto alloc = [&](size_t bytes) {
    char* p = ws + off;
    off = (off + bytes + 255) & ~(size_t)255;
    return p;
  };
  float* dis = (float*)alloc((size_t)NN * 4);
  int* cnt = (int*)alloc((size_t)NN * 4);   // degrees, then fill counters
  int* offs = (int*)alloc((size_t)(NN + 1) * 4);
  int* bsum = (int*)alloc(1024 * 4);
  int* bbase = (int*)alloc(1024 * 4);
  int* csr = (int*)alloc((size_t)EE * 4);
  unsigned short* W1h = (unsigned short*)alloc((size_t)CC * CC * 2);
  unsigned short* W1l = (unsigned short*)alloc((size_t)CC * CC * 2);
  unsigned short* W2h = (unsigned short*)alloc((size_t)CC * CC * 2);
  unsigned short* W2l = (unsigned short*)alloc((size_t)CC * CC * 2);
  _Float16* hsbuf = (_Float16*)alloc((size_t)NN * CC * 2);  // GEMM out (fp16)
  float* h1 = (float*)alloc((size_t)NN * CC * 4);           // layer-1 activations

  hipMemsetAsync(cnt, 0, (size_t)NN * 4, stream);
  k_deg<<<2048, 256, 0, stream>>>(dst, cnt, EE);
  const int nb = (NN + 1023) / 1024;  // 98
  k_scan_local<<<nb, 1024, 0, stream>>>(cnt, offs, bsum, dis, NN);
  k_scan_bsum<<<1, 128, 0, stream>>>(bsum, bbase, nb);
  k_scan_add<<<(NN + 255) / 256, 256, 0, stream>>>(offs, bbase, cnt, NN, nb);
  k_scatter<<<2048, 256, 0, stream>>>(src, dst, offs, cnt, csr, EE);
  k_wsplit2<<<512, 256, 0, stream>>>(W1, W2, W1h, W1l, W2h, W2l);

  const int gblocks = (NN + 127) / 128;
  // layer 1: hs = (x @ W1) * dis[row] (fp16); h1 = relu(dis*(agg+self) + b1)
  k_gemm_mfma<<<gblocks, 512, 0, stream>>>(x, W1h, W1l, dis, hsbuf, NN);
  k_aggregate<<<(NN + 3) / 4, 256, 0, stream>>>(hsbuf, offs, csr, dis, b1, h1, NN);
  // layer 2 + fused readout
  k_gemm_mfma<<<gblocks, 512, 0, stream>>>(h1, W2h, W2l, dis, hsbuf, NN);
  k_aggregate_final<<<(NN + 3) / 4, 256, 0, stream>>>(hsbuf, offs, csr, dis, b2, Wl, bl, out, NN);
}